// Round 11
// baseline (1276.581 us; speedup 1.0000x reference)
//
#include <hip/hip_runtime.h>

#define BB 16
#define NN 8192
#define SS 512
#define N3 (3 * NN)  // 24576 elements per batch per tensor
#define KD 14        // per-lane KNN list depth (see k_knn comment)

typedef unsigned short u16;
typedef unsigned int u32;
typedef unsigned long long u64;
typedef float v2f __attribute__((ext_vector_type(2)));

// Packed fp32 ops (VOP3P, 2 points/inst). Per-half rounding is IEEE rn —
// bit-identical to scalar __fadd_rn/__fmul_rn.
__device__ __forceinline__ v2f pk_add(v2f a, v2f b) {
  v2f r;
  asm("v_pk_add_f32 %0, %1, %2" : "=v"(r) : "v"(a), "v"(b));
  return r;
}
__device__ __forceinline__ v2f pk_mul(v2f a, v2f b) {
  v2f r;
  asm("v_pk_mul_f32 %0, %1, %2" : "=v"(r) : "v"(a), "v"(b));
  return r;
}

template <int CTRL>
__device__ __forceinline__ float dpp_maxf(float x) {
  // old=0 is the identity for max of non-negative values
  int m = __builtin_amdgcn_update_dpp(0, __float_as_int(x), CTRL, 0xf, 0xf, false);
  return fmaxf(x, __int_as_float(m));
}
template <int CTRL>
__device__ __forceinline__ u32 dpp_maxu(u32 x) {
  u32 m = (u32)__builtin_amdgcn_update_dpp(0, (int)x, CTRL, 0xf, 0xf, false);
  return (x > m) ? x : m;
}

// ---------------------------------------------------------------------------
// K1: farthest point sampling, fp32, bit-exact vs numpy. 256 thr/block,
// 32 pts/thread (v2f regs, asm-pinned), 1 wave/SIMD. r11: SINGLE barrier per
// iteration. Per-wave: value DPP max -> readlane(63) broadcast -> find pass
// vs WAVE max (exact bit-equality; tracks coords via cndmask) -> cand DPP max
// -> owner lane publishes packed (vmax<<32|NN-idx) key + coords to LDS.
// Post-barrier: lexicographic max over 4 slots = (max dist, tie -> lowest
// idx) = np.argmax semantics; coords read from LDS (no global center load).
// r10 evidence: per-SIMD VALU issue only ~700 of 2770 cyc/iter — the rest
// was 2 barriers + 2 LDS round-trips + center load, all removed/merged here.
// ---------------------------------------------------------------------------
__global__ __attribute__((amdgpu_flat_work_group_size(256, 256),
                          amdgpu_waves_per_eu(1, 1)))
void k_fps(const float* __restrict__ xyz, float* __restrict__ out_kp) {
  __shared__ int sIdx[SS];
  __shared__ u64 rkey[2][4];
  __shared__ float rcx[2][4], rcy[2][4], rcz[2][4];
  int b = blockIdx.x, t = threadIdx.x;
  const float* base = xyz + b * N3;
  v2f px[16], py[16], pz[16], dm[16];
#pragma unroll
  for (int j = 0; j < 16; ++j) {
    int n0 = j * 512 + t, n1 = n0 + 256;  // coalesced, disjoint cover [0,8192)
    px[j] = v2f{base[n0], base[n1]};
    py[j] = v2f{base[NN + n0], base[NN + n1]};
    pz[j] = v2f{base[2 * NN + n0], base[2 * NN + n1]};
    dm[j] = v2f{1e10f, 1e10f};
  }
#pragma unroll
  for (int j = 0; j < 16; ++j) {
    // Opaque def: blocks rematerialization of the global loads.
    asm volatile("" : "+v"(px[j]), "+v"(py[j]), "+v"(pz[j]));
  }
  float cx = base[0], cy = base[NN], cz = base[2 * NN];
  int far = 0;
  int lane = t & 63, w = t >> 6;
  u32 tb = (u32)(NN - t);  // candidate base: cand = NN - gidx (1..8192; 0=none)
  for (int it = 0; it < SS; ++it) {
    if (t == 0) sIdx[it] = far;  // scan emits carry BEFORE update: idx[0]=0
    v2f ncx = v2f{-cx, -cx}, ncy = v2f{-cy, -cy}, ncz = v2f{-cz, -cz};
    float vmA = 0.0f, vmB = 0.0f;  // two accumulators: shorter dep chains
#pragma unroll
    for (int j = 0; j < 16; ++j) {
      v2f dx = pk_add(px[j], ncx);  // a + (-c) == a - c exactly
      v2f dy = pk_add(py[j], ncy);
      v2f dz = pk_add(pz[j], ncz);
      v2f xx = pk_mul(dx, dx);
      v2f yy = pk_mul(dy, dy);
      v2f s = pk_add(xx, yy);
      v2f zz = pk_mul(dz, dz);
      v2f d = pk_add(s, zz);  // ((dx^2+dy^2)+dz^2), numpy tree per half
      float a0 = fminf(dm[j].x, d.x);
      float a1 = fminf(dm[j].y, d.y);
      dm[j].x = a0;
      dm[j].y = a1;
      vmA = fmaxf(vmA, a0);
      vmB = fmaxf(vmB, a1);
    }
    float vmax = fmaxf(vmA, vmB);
    vmax = dpp_maxf<0x111>(vmax);  // row_shr:1
    vmax = dpp_maxf<0x112>(vmax);  // row_shr:2
    vmax = dpp_maxf<0x114>(vmax);  // row_shr:4
    vmax = dpp_maxf<0x118>(vmax);  // row_shr:8
    vmax = dpp_maxf<0x142>(vmax);  // row_bcast:15
    vmax = dpp_maxf<0x143>(vmax);  // row_bcast:31 -> lane63 = wave max
    float wv = __int_as_float(__builtin_amdgcn_readlane(__float_as_int(vmax), 63));
    // find pass vs wave max (exact: wv IS one of this wave's dm values).
    // Descending gidx order: last write = lowest gidx. Coords tracked too.
    u32 cand = 0;
    float bx = 0.f, by = 0.f, bz = 0.f;
#pragma unroll
    for (int j = 15; j >= 0; --j) {
      bool m1 = (dm[j].y == wv);
      cand = m1 ? (tb - (u32)(j * 512 + 256)) : cand;
      bx = m1 ? px[j].y : bx;
      by = m1 ? py[j].y : by;
      bz = m1 ? pz[j].y : bz;
      bool m0 = (dm[j].x == wv);
      cand = m0 ? (tb - (u32)(j * 512)) : cand;
      bx = m0 ? px[j].x : bx;
      by = m0 ? py[j].x : by;
      bz = m0 ? pz[j].x : bz;
    }
    u32 cl = cand;
    cand = dpp_maxu<0x111>(cand);
    cand = dpp_maxu<0x112>(cand);
    cand = dpp_maxu<0x114>(cand);
    cand = dpp_maxu<0x118>(cand);
    cand = dpp_maxu<0x142>(cand);
    cand = dpp_maxu<0x143>(cand);  // lane63 = wave best (max cand = min gidx)
    u32 wc = (u32)__builtin_amdgcn_readlane((int)cand, 63);
    int pb = it & 1;  // parity double-buffer (WAR separated by the barrier)
    if (cl == wc) {   // unique owner: gidx sets are disjoint across lanes
      rkey[pb][w] = ((u64)__float_as_uint(wv) << 32) | wc;
      rcx[pb][w] = bx;
      rcy[pb][w] = by;
      rcz[pb][w] = bz;
    }
    __syncthreads();  // the only barrier per iteration
    u64 k0 = rkey[pb][0], k1 = rkey[pb][1];
    u64 k2 = rkey[pb][2], k3 = rkey[pb][3];
    int w01 = (k1 > k0) ? 1 : 0;
    u64 k01 = (k1 > k0) ? k1 : k0;
    int w23 = (k3 > k2) ? 3 : 2;
    u64 k23 = (k3 > k2) ? k3 : k2;
    int wb = (k23 > k01) ? w23 : w01;
    u64 kg = (k23 > k01) ? k23 : k01;
    far = NN - (int)(u32)(kg & 0xffffffffu);
    cx = rcx[pb][wb];
    cy = rcy[pb][wb];
    cz = rcz[pb][wb];
  }
  __syncthreads();
  for (int i = t; i < SS; i += 256) {
    int id = sIdx[i];
    out_kp[b * 1536 + i] = base[id];  // exact fp32 copies
    out_kp[b * 1536 + SS + i] = base[NN + id];
    out_kp[b * 1536 + 2 * SS + i] = base[2 * NN + id];
  }
}

// ---------------------------------------------------------------------------
// K2: per (b,s) row, sorted top-24 nearest (dist asc, idx asc) — prefixes give
// K=8/16/24 and base K=16 (lax.top_k stable tie-break). One wave per row.
// r11: per-lane list depth KD=14 (was 24): the wave-coherent u64 insertion
// runs every chunk, so depth dominates k_knn's VALU. Top-24 indices are
// ~uniform mod 64 (random coords), P(any lane holds >=15 of the 24) < 1e-15
// over all rows — exact in practice. Merge still pops the global top-24.
// d = (|a|^2+|q|^2) - 2*dot, all rn ops, matching the numpy expression tree.
// ---------------------------------------------------------------------------
__global__ __launch_bounds__(256) void k_knn(const float* __restrict__ xyz,
                                             const float* __restrict__ kp,
                                             u16* __restrict__ knn) {
  int t = threadIdx.x;
  int row = blockIdx.x * 4 + (t >> 6);
  int lane = t & 63;
  int b = row >> 9, s = row & (SS - 1);
  const float* base = xyz + b * N3;
  float ax = kp[b * 1536 + s];
  float ay = kp[b * 1536 + SS + s];
  float az = kp[b * 1536 + 2 * SS + s];
  float aw = __fadd_rn(__fadd_rn(__fmul_rn(ax, ax), __fmul_rn(ay, ay)), __fmul_rn(az, az));
  u64 arr[KD];
#pragma unroll
  for (int i = 0; i < KD; ++i) arr[i] = ~0ull;
  for (int c = 0; c < 128; ++c) {
    int n = c * 64 + lane;
    float qx = base[n], qy = base[NN + n], qz = base[2 * NN + n];
    float qw = __fadd_rn(__fadd_rn(__fmul_rn(qx, qx), __fmul_rn(qy, qy)), __fmul_rn(qz, qz));
    float dot = __fadd_rn(__fadd_rn(__fmul_rn(ax, qx), __fmul_rn(ay, qy)), __fmul_rn(az, qz));
    float d = __fsub_rn(__fadd_rn(aw, qw), __fmul_rn(2.0f, dot));
    u32 ub = __float_as_uint(d);
    ub ^= (ub & 0x80000000u) ? 0xFFFFFFFFu : 0x80000000u;  // order-preserving map
    u64 key = ((u64)ub << 32) | (u32)n;
    if (key < arr[KD - 1]) {  // branchless descending insertion (arr asc)
#pragma unroll
      for (int i = KD - 1; i >= 1; --i) {
        u64 am = arr[i - 1];
        arr[i] = (am > key) ? am : ((arr[i] > key) ? key : arr[i]);
      }
      if (arr[0] > key) arr[0] = key;
    }
  }
  // merge 64 sorted lists: 24 x (wave-min of heads, winner pops). keys unique.
  u64 mine = 0;
  for (int it = 0; it < 24; ++it) {
    u64 m = arr[0];
#pragma unroll
    for (int off = 1; off < 64; off <<= 1) {
      u64 o = __shfl_xor(m, off, 64);
      m = (o < m) ? o : m;
    }
    if (lane == it) mine = m;
    if (arr[0] == m) {
#pragma unroll
      for (int i = 0; i < KD - 1; ++i) arr[i] = arr[i + 1];
      arr[KD - 1] = ~0ull;
    }
  }
  if (lane < 24) knn[row * 24 + lane] = (u16)(mine & 0xFFFFu);
}

// ---------------------------------------------------------------------------
// K3: base SA MLP. feat[16][6] = [rel_xyz | pts]; 6->64 relu -> 64->128; max
// over K=16. Wave = one row; each thread owns 2 output channels (lane,
// lane+64) with W2 rows in registers; h1 read as explicit float4 broadcast.
// Block = 4 rows in flight x 2 groups = 8 rows.
// ---------------------------------------------------------------------------
__global__ __launch_bounds__(256) void k_base(
    const float* __restrict__ xyz, const float* __restrict__ pts,
    const float* __restrict__ kp, const u16* __restrict__ knn,
    const float* __restrict__ W1, const float* __restrict__ b1,
    const float* __restrict__ W2, const float* __restrict__ b2,
    float* __restrict__ out) {
  __shared__ float sW1T[6 * 64];     // [c][o]
  __shared__ float sb1[64];
  __shared__ float sfeat[4][16 * 6]; // [row][k*6+c]
  __shared__ float sh1[4][16 * 64];  // [row][k*64+o]
  int t = threadIdx.x, lane = t & 63, w = t >> 6;
  int b = blockIdx.x >> 6, s0 = (blockIdx.x & 63) * 8;
  for (int i = t; i < 384; i += 256) {
    int o = i / 6, c = i - o * 6;
    sW1T[c * 64 + o] = W1[i];
  }
  if (t < 64) sb1[t] = b1[t];
  float wgtA[64], wgtB[64];
#pragma unroll
  for (int j = 0; j < 64; ++j) {
    wgtA[j] = W2[lane * 64 + j];
    wgtB[j] = W2[(lane + 64) * 64 + j];
  }
  float b2A = b2[lane], b2B = b2[lane + 64];
  __syncthreads();
  for (int g = 0; g < 2; ++g) {
    for (int i = t; i < 384; i += 256) {  // 4 rows x 16 k x 6 c
      int rr = i / 96, rem = i - rr * 96, k = rem / 6, c = rem - k * 6;
      int s = s0 + g * 4 + rr, row = b * SS + s;
      int id = knn[row * 24 + k];  // first 16 of sorted top-24 = base KNN
      float val;
      if (c < 3) {
        val = __fsub_rn(xyz[b * N3 + c * NN + id], kp[b * 1536 + c * SS + s]);
      } else {
        val = pts[b * N3 + (c - 3) * NN + id];
      }
      sfeat[rr][k * 6 + c] = val;
    }
    __syncthreads();
#pragma unroll
    for (int m = 0; m < 16; ++m) {  // 4 rows x 1024 h1 entries / 256 thr
      int u = m * 256 + t;
      int rr = u >> 10, rem = u & 1023, k = rem >> 6, o = rem & 63;
      float acc = sb1[o];
#pragma unroll
      for (int c = 0; c < 6; ++c) acc = fmaf(sfeat[rr][k * 6 + c], sW1T[c * 64 + o], acc);
      sh1[rr][k * 64 + o] = fmaxf(acc, 0.f);
    }
    __syncthreads();
    float bestA = -1e30f, bestB = -1e30f;
#pragma unroll
    for (int k = 0; k < 16; ++k) {
      const float4* h4 = (const float4*)&sh1[w][k * 64];  // wave-uniform bcast
      float a0 = 0.f, a1 = 0.f;
#pragma unroll
      for (int j = 0; j < 16; ++j) {
        float4 hv = h4[j];
        a0 = fmaf(hv.x, wgtA[4 * j], a0);
        a0 = fmaf(hv.y, wgtA[4 * j + 1], a0);
        a0 = fmaf(hv.z, wgtA[4 * j + 2], a0);
        a0 = fmaf(hv.w, wgtA[4 * j + 3], a0);
        a1 = fmaf(hv.x, wgtB[4 * j], a1);
        a1 = fmaf(hv.y, wgtB[4 * j + 1], a1);
        a1 = fmaf(hv.z, wgtB[4 * j + 2], a1);
        a1 = fmaf(hv.w, wgtB[4 * j + 3], a1);
      }
      bestA = fmaxf(bestA, a0);
      bestB = fmaxf(bestB, a1);
    }
    int s = s0 + g * 4 + w;
    out[24576 + b * 262144 + lane * 512 + s] = bestA + b2A;
    out[24576 + b * 262144 + (lane + 64) * 512 + s] = bestB + b2B;
    __syncthreads();  // protect sfeat/sh1 before next group overwrites
  }
}

// ---------------------------------------------------------------------------
// K4: multi-scale MLPs, scale = blockIdx.y, K = 8*(scale+1), rel-xyz only.
// Same 2-channels-per-thread structure. Output channels 128*(scale+1)..+128.
// ---------------------------------------------------------------------------
__global__ __launch_bounds__(256) void k_ms(
    const float* __restrict__ xyz, const float* __restrict__ kp,
    const u16* __restrict__ knn, const float* __restrict__ msW1,
    const float* __restrict__ msb1, const float* __restrict__ msW2,
    const float* __restrict__ msb2, float* __restrict__ out) {
  int scale = blockIdx.y;
  int kk = 8 * (scale + 1);
  __shared__ float sW1T[3 * 64];
  __shared__ float sb1[64];
  __shared__ float sfeat[4][24 * 3];
  __shared__ float sh1[4][24 * 64];
  int t = threadIdx.x, lane = t & 63, w = t >> 6;
  int b = blockIdx.x >> 6, s0 = (blockIdx.x & 63) * 8;
  const float* W1s = msW1 + scale * 192;
  for (int i = t; i < 192; i += 256) {
    int o = i / 3, c = i - o * 3;
    sW1T[c * 64 + o] = W1s[i];
  }
  if (t < 64) sb1[t] = msb1[scale * 64 + t];
  float wgtA[64], wgtB[64];
#pragma unroll
  for (int j = 0; j < 64; ++j) {
    wgtA[j] = msW2[scale * 8192 + lane * 64 + j];
    wgtB[j] = msW2[scale * 8192 + (lane + 64) * 64 + j];
  }
  float b2A = msb2[scale * 128 + lane], b2B = msb2[scale * 128 + lane + 64];
  __syncthreads();
  int co = 128 * (scale + 1);
  for (int g = 0; g < 2; ++g) {
    int nfeat = 4 * kk * 3;
    for (int i = t; i < nfeat; i += 256) {  // 4 rows x kk k x 3 c
      int kk3 = kk * 3;
      int rr = i / kk3, rem = i - rr * kk3, k = rem / 3, c = rem - k * 3;
      int s = s0 + g * 4 + rr, row = b * SS + s;
      int id = knn[row * 24 + k];
      sfeat[rr][k * 3 + c] = __fsub_rn(xyz[b * N3 + c * NN + id], kp[b * 1536 + c * SS + s]);
    }
    __syncthreads();
    for (int rr = 0; rr < 4; ++rr) {  // h1 for kk*64 entries per row
      for (int u = t; u < kk * 64; u += 256) {
        int k = u >> 6, o = u & 63;
        float acc = sb1[o];
        acc = fmaf(sfeat[rr][k * 3 + 0], sW1T[o], acc);
        acc = fmaf(sfeat[rr][k * 3 + 1], sW1T[64 + o], acc);
        acc = fmaf(sfeat[rr][k * 3 + 2], sW1T[128 + o], acc);
        sh1[rr][k * 64 + o] = fmaxf(acc, 0.f);
      }
    }
    __syncthreads();
    float bestA = -1e30f, bestB = -1e30f;
    for (int k = 0; k < kk; ++k) {  // kk uniform across block -> no divergence
      const float4* h4 = (const float4*)&sh1[w][k * 64];
      float a0 = 0.f, a1 = 0.f;
#pragma unroll
      for (int j = 0; j < 16; ++j) {
        float4 hv = h4[j];
        a0 = fmaf(hv.x, wgtA[4 * j], a0);
        a0 = fmaf(hv.y, wgtA[4 * j + 1], a0);
        a0 = fmaf(hv.z, wgtA[4 * j + 2], a0);
        a0 = fmaf(hv.w, wgtA[4 * j + 3], a0);
        a1 = fmaf(hv.x, wgtB[4 * j], a1);
        a1 = fmaf(hv.y, wgtB[4 * j + 1], a1);
        a1 = fmaf(hv.z, wgtB[4 * j + 2], a1);
        a1 = fmaf(hv.w, wgtB[4 * j + 3], a1);
      }
      bestA = fmaxf(bestA, a0);
      bestB = fmaxf(bestB, a1);
    }
    int s = s0 + g * 4 + w;
    out[24576 + b * 262144 + (co + lane) * 512 + s] = bestA + b2A;
    out[24576 + b * 262144 + (co + lane + 64) * 512 + s] = bestB + b2B;
    __syncthreads();
  }
}

// ---------------------------------------------------------------------------
extern "C" void kernel_launch(void* const* d_in, const int* in_sizes, int n_in,
                              void* d_out, int out_size, void* d_ws, size_t ws_size,
                              hipStream_t stream) {
  const float* xyz = (const float*)d_in[0];    // l0_xyz  [B,3,N] f32
  const float* pts = (const float*)d_in[1];    // l0_points
  const float* sa_W1 = (const float*)d_in[2];  // [64,6]
  const float* sa_b1 = (const float*)d_in[3];  // [64]
  const float* sa_W2 = (const float*)d_in[4];  // [128,64]
  const float* sa_b2 = (const float*)d_in[5];  // [128]
  const float* ms_W1 = (const float*)d_in[6];  // [3,64,3]
  const float* ms_b1 = (const float*)d_in[7];  // [3,64]
  const float* ms_W2 = (const float*)d_in[8];  // [3,128,64]
  const float* ms_b2 = (const float*)d_in[9];  // [3,128]
  float* out = (float*)d_out;
  const float* kp = (const float*)d_out;  // keypoints written by k_fps

  // workspace: knn u16[B*S*24] = 384 KB
  u16* knn = (u16*)d_ws;

  k_fps<<<BB, 256, 0, stream>>>(xyz, out);
  k_knn<<<(BB * SS) / 4, 256, 0, stream>>>(xyz, kp, knn);
  k_base<<<BB * 64, 256, 0, stream>>>(xyz, pts, kp, knn, sa_W1, sa_b1, sa_W2, sa_b2, out);
  k_ms<<<dim3(BB * 64, 3), 256, 0, stream>>>(xyz, kp, knn, ms_W1, ms_b1, ms_W2, ms_b2, out);
}

// Round 12
// 1086.896 us; speedup vs baseline: 1.1745x; 1.1745x over previous
//
#include <hip/hip_runtime.h>

#define BB 16
#define NN 8192
#define SS 512
#define N3 (3 * NN)  // 24576 elements per batch per tensor
#define KD 14        // per-lane KNN list depth (see k_knn comment)

typedef unsigned short u16;
typedef unsigned int u32;
typedef unsigned long long u64;
typedef float v2f __attribute__((ext_vector_type(2)));

// Packed fp32 ops (VOP3P, 2 points/inst). Per-half rounding is IEEE rn —
// bit-identical to scalar __fadd_rn/__fmul_rn.
__device__ __forceinline__ v2f pk_add(v2f a, v2f b) {
  v2f r;
  asm("v_pk_add_f32 %0, %1, %2" : "=v"(r) : "v"(a), "v"(b));
  return r;
}
__device__ __forceinline__ v2f pk_mul(v2f a, v2f b) {
  v2f r;
  asm("v_pk_mul_f32 %0, %1, %2" : "=v"(r) : "v"(a), "v"(b));
  return r;
}

template <int CTRL>
__device__ __forceinline__ float dpp_maxf(float x) {
  // old=0 is the identity for max of non-negative values
  int m = __builtin_amdgcn_update_dpp(0, __float_as_int(x), CTRL, 0xf, 0xf, false);
  return fmaxf(x, __int_as_float(m));
}
template <int CTRL>
__device__ __forceinline__ u32 dpp_maxu(u32 x) {
  u32 m = (u32)__builtin_amdgcn_update_dpp(0, (int)x, CTRL, 0xf, 0xf, false);
  return (x > m) ? x : m;
}

// ---------------------------------------------------------------------------
// K1: farthest point sampling, fp32, bit-exact vs numpy. EXACT r10 version —
// best measured (591 us). 256 thr/block, 32 pts/thread (v2f regs, asm-pinned),
// 1 wave/SIMD. Scan tracks NO indices/coords — packed dmin update + running
// value-max; argmax recovered by equality find-pass vs the global max (exact
// bit-compare); cand = NN - gidx so umax => lowest index (np.argmax
// tie-break; descending scan preserves it within-thread). Winner coords via
// uniform global re-load. r11's 1-barrier + coord-cndmask + LDS-coords
// variant REGRESSED to ~810 us (DPP->readlane hazards + dependent LDS chain
// + exec-masked write cost ~1000 cyc/iter) — do not reintroduce.
// ---------------------------------------------------------------------------
__global__ __attribute__((amdgpu_flat_work_group_size(256, 256),
                          amdgpu_waves_per_eu(1, 1)))
void k_fps(const float* __restrict__ xyz, float* __restrict__ out_kp) {
  __shared__ int sIdx[SS];
  __shared__ float sv[4];
  __shared__ u32 si[4];
  int b = blockIdx.x, t = threadIdx.x;
  const float* base = xyz + b * N3;
  v2f px[16], py[16], pz[16], dm[16];
#pragma unroll
  for (int j = 0; j < 16; ++j) {
    int n0 = j * 512 + t, n1 = n0 + 256;  // coalesced, disjoint cover [0,8192)
    px[j] = v2f{base[n0], base[n1]};
    py[j] = v2f{base[NN + n0], base[NN + n1]};
    pz[j] = v2f{base[2 * NN + n0], base[2 * NN + n1]};
    dm[j] = v2f{1e10f, 1e10f};
  }
#pragma unroll
  for (int j = 0; j < 16; ++j) {
    // Opaque def: blocks rematerialization of the global loads.
    asm volatile("" : "+v"(px[j]), "+v"(py[j]), "+v"(pz[j]));
  }
  float cx = base[0], cy = base[NN], cz = base[2 * NN];
  int far = 0;
  int lane = t & 63, w = t >> 6;
  u32 tb = (u32)(NN - t);  // candidate base: cand = NN - gidx (1..8192; 0=none)
  for (int it = 0; it < SS; ++it) {
    if (t == 0) sIdx[it] = far;  // scan emits carry BEFORE update: idx[0]=0
    // negated center, broadcast to both halves (a + (-c) == a - c exactly)
    v2f ncx = v2f{-cx, -cx}, ncy = v2f{-cy, -cy}, ncz = v2f{-cz, -cz};
    float vmax = 0.0f;
#pragma unroll
    for (int j = 0; j < 16; ++j) {
      v2f dx = pk_add(px[j], ncx);
      v2f dy = pk_add(py[j], ncy);
      v2f dz = pk_add(pz[j], ncz);
      v2f xx = pk_mul(dx, dx);
      v2f yy = pk_mul(dy, dy);
      v2f s = pk_add(xx, yy);
      v2f zz = pk_mul(dz, dz);
      v2f d = pk_add(s, zz);  // ((dx^2+dy^2)+dz^2), numpy tree per half
      float a0 = fminf(dm[j].x, d.x);
      float a1 = fminf(dm[j].y, d.y);
      dm[j].x = a0;
      dm[j].y = a1;
      vmax = fmaxf(vmax, a0);
      vmax = fmaxf(vmax, a1);
    }
    // wave max of vmax (single chain, distances >= 0)
    vmax = dpp_maxf<0x111>(vmax);  // row_shr:1
    vmax = dpp_maxf<0x112>(vmax);  // row_shr:2
    vmax = dpp_maxf<0x114>(vmax);  // row_shr:4
    vmax = dpp_maxf<0x118>(vmax);  // row_shr:8
    vmax = dpp_maxf<0x142>(vmax);  // row_bcast:15
    vmax = dpp_maxf<0x143>(vmax);  // row_bcast:31 -> lane63 = wave max
    if (lane == 63) sv[w] = vmax;
    __syncthreads();  // barrier 1: sv ready
    float vg = fmaxf(fmaxf(sv[0], sv[1]), fmaxf(sv[2], sv[3]));
    // find pass: exact bit-equality with vg; descending gidx order so the
    // LAST write (lowest gidx) wins within the thread.
    u32 cand = 0;
#pragma unroll
    for (int j = 15; j >= 0; --j) {
      u32 v1 = tb - (u32)(j * 512 + 256);  // cand for .y half (higher gidx)
      u32 v0 = tb - (u32)(j * 512);        // cand for .x half
      cand = (dm[j].y == vg) ? v1 : cand;
      cand = (dm[j].x == vg) ? v0 : cand;
    }
    cand = dpp_maxu<0x111>(cand);
    cand = dpp_maxu<0x112>(cand);
    cand = dpp_maxu<0x114>(cand);
    cand = dpp_maxu<0x118>(cand);
    cand = dpp_maxu<0x142>(cand);
    cand = dpp_maxu<0x143>(cand);  // lane63 = wave best (max cand = min gidx)
    if (lane == 63) si[w] = cand;
    __syncthreads();  // barrier 2: si ready
    u32 c01 = (si[0] > si[1]) ? si[0] : si[1];
    u32 c23 = (si[2] > si[3]) ? si[2] : si[3];
    u32 cg = (c01 > c23) ? c01 : c23;
    far = NN - (int)cg;
    // uniform coord re-load (all lanes same address -> one transaction)
    cx = base[far];
    cy = base[NN + far];
    cz = base[2 * NN + far];
  }
  __syncthreads();
  for (int i = t; i < SS; i += 256) {
    int id = sIdx[i];
    out_kp[b * 1536 + i] = base[id];  // exact fp32 copies
    out_kp[b * 1536 + SS + i] = base[NN + id];
    out_kp[b * 1536 + 2 * SS + i] = base[2 * NN + id];
  }
}

// ---------------------------------------------------------------------------
// K2: per (b,s) row, sorted top-24 nearest (dist asc, idx asc) — prefixes give
// K=8/16/24 and base K=16 (lax.top_k stable tie-break). One wave per row.
// KD=14 per-lane depth (r11 win: non-fps time 634 -> 466 us): top-24 indices
// are ~uniform mod 64, P(any lane holds >=15 of 24) < 1e-15 over all rows.
// d = (|a|^2+|q|^2) - 2*dot, all rn ops, matching the numpy expression tree.
// ---------------------------------------------------------------------------
__global__ __launch_bounds__(256) void k_knn(const float* __restrict__ xyz,
                                             const float* __restrict__ kp,
                                             u16* __restrict__ knn) {
  int t = threadIdx.x;
  int row = blockIdx.x * 4 + (t >> 6);
  int lane = t & 63;
  int b = row >> 9, s = row & (SS - 1);
  const float* base = xyz + b * N3;
  float ax = kp[b * 1536 + s];
  float ay = kp[b * 1536 + SS + s];
  float az = kp[b * 1536 + 2 * SS + s];
  float aw = __fadd_rn(__fadd_rn(__fmul_rn(ax, ax), __fmul_rn(ay, ay)), __fmul_rn(az, az));
  u64 arr[KD];
#pragma unroll
  for (int i = 0; i < KD; ++i) arr[i] = ~0ull;
  for (int c = 0; c < 128; ++c) {
    int n = c * 64 + lane;
    float qx = base[n], qy = base[NN + n], qz = base[2 * NN + n];
    float qw = __fadd_rn(__fadd_rn(__fmul_rn(qx, qx), __fmul_rn(qy, qy)), __fmul_rn(qz, qz));
    float dot = __fadd_rn(__fadd_rn(__fmul_rn(ax, qx), __fmul_rn(ay, qy)), __fmul_rn(az, qz));
    float d = __fsub_rn(__fadd_rn(aw, qw), __fmul_rn(2.0f, dot));
    u32 ub = __float_as_uint(d);
    ub ^= (ub & 0x80000000u) ? 0xFFFFFFFFu : 0x80000000u;  // order-preserving map
    u64 key = ((u64)ub << 32) | (u32)n;
    if (key < arr[KD - 1]) {  // branchless descending insertion (arr asc)
#pragma unroll
      for (int i = KD - 1; i >= 1; --i) {
        u64 am = arr[i - 1];
        arr[i] = (am > key) ? am : ((arr[i] > key) ? key : arr[i]);
      }
      if (arr[0] > key) arr[0] = key;
    }
  }
  // merge 64 sorted lists: 24 x (wave-min of heads, winner pops). keys unique.
  u64 mine = 0;
  for (int it = 0; it < 24; ++it) {
    u64 m = arr[0];
#pragma unroll
    for (int off = 1; off < 64; off <<= 1) {
      u64 o = __shfl_xor(m, off, 64);
      m = (o < m) ? o : m;
    }
    if (lane == it) mine = m;
    if (arr[0] == m) {
#pragma unroll
      for (int i = 0; i < KD - 1; ++i) arr[i] = arr[i + 1];
      arr[KD - 1] = ~0ull;
    }
  }
  if (lane < 24) knn[row * 24 + lane] = (u16)(mine & 0xFFFFu);
}

// ---------------------------------------------------------------------------
// K3: base SA MLP. feat[16][6] = [rel_xyz | pts]; 6->64 relu -> 64->128; max
// over K=16. Wave = one row; each thread owns 2 output channels (lane,
// lane+64) with W2 rows in registers; h1 read as explicit float4 broadcast.
// Block = 4 rows in flight x 2 groups = 8 rows.
// ---------------------------------------------------------------------------
__global__ __launch_bounds__(256) void k_base(
    const float* __restrict__ xyz, const float* __restrict__ pts,
    const float* __restrict__ kp, const u16* __restrict__ knn,
    const float* __restrict__ W1, const float* __restrict__ b1,
    const float* __restrict__ W2, const float* __restrict__ b2,
    float* __restrict__ out) {
  __shared__ float sW1T[6 * 64];     // [c][o]
  __shared__ float sb1[64];
  __shared__ float sfeat[4][16 * 6]; // [row][k*6+c]
  __shared__ float sh1[4][16 * 64];  // [row][k*64+o]
  int t = threadIdx.x, lane = t & 63, w = t >> 6;
  int b = blockIdx.x >> 6, s0 = (blockIdx.x & 63) * 8;
  for (int i = t; i < 384; i += 256) {
    int o = i / 6, c = i - o * 6;
    sW1T[c * 64 + o] = W1[i];
  }
  if (t < 64) sb1[t] = b1[t];
  float wgtA[64], wgtB[64];
#pragma unroll
  for (int j = 0; j < 64; ++j) {
    wgtA[j] = W2[lane * 64 + j];
    wgtB[j] = W2[(lane + 64) * 64 + j];
  }
  float b2A = b2[lane], b2B = b2[lane + 64];
  __syncthreads();
  for (int g = 0; g < 2; ++g) {
    for (int i = t; i < 384; i += 256) {  // 4 rows x 16 k x 6 c
      int rr = i / 96, rem = i - rr * 96, k = rem / 6, c = rem - k * 6;
      int s = s0 + g * 4 + rr, row = b * SS + s;
      int id = knn[row * 24 + k];  // first 16 of sorted top-24 = base KNN
      float val;
      if (c < 3) {
        val = __fsub_rn(xyz[b * N3 + c * NN + id], kp[b * 1536 + c * SS + s]);
      } else {
        val = pts[b * N3 + (c - 3) * NN + id];
      }
      sfeat[rr][k * 6 + c] = val;
    }
    __syncthreads();
#pragma unroll
    for (int m = 0; m < 16; ++m) {  // 4 rows x 1024 h1 entries / 256 thr
      int u = m * 256 + t;
      int rr = u >> 10, rem = u & 1023, k = rem >> 6, o = rem & 63;
      float acc = sb1[o];
#pragma unroll
      for (int c = 0; c < 6; ++c) acc = fmaf(sfeat[rr][k * 6 + c], sW1T[c * 64 + o], acc);
      sh1[rr][k * 64 + o] = fmaxf(acc, 0.f);
    }
    __syncthreads();
    float bestA = -1e30f, bestB = -1e30f;
#pragma unroll
    for (int k = 0; k < 16; ++k) {
      const float4* h4 = (const float4*)&sh1[w][k * 64];  // wave-uniform bcast
      float a0 = 0.f, a1 = 0.f;
#pragma unroll
      for (int j = 0; j < 16; ++j) {
        float4 hv = h4[j];
        a0 = fmaf(hv.x, wgtA[4 * j], a0);
        a0 = fmaf(hv.y, wgtA[4 * j + 1], a0);
        a0 = fmaf(hv.z, wgtA[4 * j + 2], a0);
        a0 = fmaf(hv.w, wgtA[4 * j + 3], a0);
        a1 = fmaf(hv.x, wgtB[4 * j], a1);
        a1 = fmaf(hv.y, wgtB[4 * j + 1], a1);
        a1 = fmaf(hv.z, wgtB[4 * j + 2], a1);
        a1 = fmaf(hv.w, wgtB[4 * j + 3], a1);
      }
      bestA = fmaxf(bestA, a0);
      bestB = fmaxf(bestB, a1);
    }
    int s = s0 + g * 4 + w;
    out[24576 + b * 262144 + lane * 512 + s] = bestA + b2A;
    out[24576 + b * 262144 + (lane + 64) * 512 + s] = bestB + b2B;
    __syncthreads();  // protect sfeat/sh1 before next group overwrites
  }
}

// ---------------------------------------------------------------------------
// K4: multi-scale MLPs, scale = blockIdx.y, K = 8*(scale+1), rel-xyz only.
// Same 2-channels-per-thread structure. Output channels 128*(scale+1)..+128.
// ---------------------------------------------------------------------------
__global__ __launch_bounds__(256) void k_ms(
    const float* __restrict__ xyz, const float* __restrict__ kp,
    const u16* __restrict__ knn, const float* __restrict__ msW1,
    const float* __restrict__ msb1, const float* __restrict__ msW2,
    const float* __restrict__ msb2, float* __restrict__ out) {
  int scale = blockIdx.y;
  int kk = 8 * (scale + 1);
  __shared__ float sW1T[3 * 64];
  __shared__ float sb1[64];
  __shared__ float sfeat[4][24 * 3];
  __shared__ float sh1[4][24 * 64];
  int t = threadIdx.x, lane = t & 63, w = t >> 6;
  int b = blockIdx.x >> 6, s0 = (blockIdx.x & 63) * 8;
  const float* W1s = msW1 + scale * 192;
  for (int i = t; i < 192; i += 256) {
    int o = i / 3, c = i - o * 3;
    sW1T[c * 64 + o] = W1s[i];
  }
  if (t < 64) sb1[t] = msb1[scale * 64 + t];
  float wgtA[64], wgtB[64];
#pragma unroll
  for (int j = 0; j < 64; ++j) {
    wgtA[j] = msW2[scale * 8192 + lane * 64 + j];
    wgtB[j] = msW2[scale * 8192 + (lane + 64) * 64 + j];
  }
  float b2A = msb2[scale * 128 + lane], b2B = msb2[scale * 128 + lane + 64];
  __syncthreads();
  int co = 128 * (scale + 1);
  for (int g = 0; g < 2; ++g) {
    int nfeat = 4 * kk * 3;
    for (int i = t; i < nfeat; i += 256) {  // 4 rows x kk k x 3 c
      int kk3 = kk * 3;
      int rr = i / kk3, rem = i - rr * kk3, k = rem / 3, c = rem - k * 3;
      int s = s0 + g * 4 + rr, row = b * SS + s;
      int id = knn[row * 24 + k];
      sfeat[rr][k * 3 + c] = __fsub_rn(xyz[b * N3 + c * NN + id], kp[b * 1536 + c * SS + s]);
    }
    __syncthreads();
    for (int rr = 0; rr < 4; ++rr) {  // h1 for kk*64 entries per row
      for (int u = t; u < kk * 64; u += 256) {
        int k = u >> 6, o = u & 63;
        float acc = sb1[o];
        acc = fmaf(sfeat[rr][k * 3 + 0], sW1T[o], acc);
        acc = fmaf(sfeat[rr][k * 3 + 1], sW1T[64 + o], acc);
        acc = fmaf(sfeat[rr][k * 3 + 2], sW1T[128 + o], acc);
        sh1[rr][k * 64 + o] = fmaxf(acc, 0.f);
      }
    }
    __syncthreads();
    float bestA = -1e30f, bestB = -1e30f;
    for (int k = 0; k < kk; ++k) {  // kk uniform across block -> no divergence
      const float4* h4 = (const float4*)&sh1[w][k * 64];
      float a0 = 0.f, a1 = 0.f;
#pragma unroll
      for (int j = 0; j < 16; ++j) {
        float4 hv = h4[j];
        a0 = fmaf(hv.x, wgtA[4 * j], a0);
        a0 = fmaf(hv.y, wgtA[4 * j + 1], a0);
        a0 = fmaf(hv.z, wgtA[4 * j + 2], a0);
        a0 = fmaf(hv.w, wgtA[4 * j + 3], a0);
        a1 = fmaf(hv.x, wgtB[4 * j], a1);
        a1 = fmaf(hv.y, wgtB[4 * j + 1], a1);
        a1 = fmaf(hv.z, wgtB[4 * j + 2], a1);
        a1 = fmaf(hv.w, wgtB[4 * j + 3], a1);
      }
      bestA = fmaxf(bestA, a0);
      bestB = fmaxf(bestB, a1);
    }
    int s = s0 + g * 4 + w;
    out[24576 + b * 262144 + (co + lane) * 512 + s] = bestA + b2A;
    out[24576 + b * 262144 + (co + lane + 64) * 512 + s] = bestB + b2B;
    __syncthreads();
  }
}

// ---------------------------------------------------------------------------
extern "C" void kernel_launch(void* const* d_in, const int* in_sizes, int n_in,
                              void* d_out, int out_size, void* d_ws, size_t ws_size,
                              hipStream_t stream) {
  const float* xyz = (const float*)d_in[0];    // l0_xyz  [B,3,N] f32
  const float* pts = (const float*)d_in[1];    // l0_points
  const float* sa_W1 = (const float*)d_in[2];  // [64,6]
  const float* sa_b1 = (const float*)d_in[3];  // [64]
  const float* sa_W2 = (const float*)d_in[4];  // [128,64]
  const float* sa_b2 = (const float*)d_in[5];  // [128]
  const float* ms_W1 = (const float*)d_in[6];  // [3,64,3]
  const float* ms_b1 = (const float*)d_in[7];  // [3,64]
  const float* ms_W2 = (const float*)d_in[8];  // [3,128,64]
  const float* ms_b2 = (const float*)d_in[9];  // [3,128]
  float* out = (float*)d_out;
  const float* kp = (const float*)d_out;  // keypoints written by k_fps

  // workspace: knn u16[B*S*24] = 384 KB
  u16* knn = (u16*)d_ws;

  k_fps<<<BB, 256, 0, stream>>>(xyz, out);
  k_knn<<<(BB * SS) / 4, 256, 0, stream>>>(xyz, kp, knn);
  k_base<<<BB * 64, 256, 0, stream>>>(xyz, pts, kp, knn, sa_W1, sa_b1, sa_W2, sa_b2, out);
  k_ms<<<dim3(BB * 64, 3), 256, 0, stream>>>(xyz, kp, knn, ms_W1, ms_b1, ms_W2, ms_b2, out);
}

// Round 13
// 1030.527 us; speedup vs baseline: 1.2388x; 1.0547x over previous
//
#include <hip/hip_runtime.h>

#define BB 16
#define NN 8192
#define SS 512
#define N3 (3 * NN)  // 24576 elements per batch per tensor
#define KD 14        // per-lane KNN list depth (see k_knn comment)

typedef unsigned short u16;
typedef unsigned int u32;
typedef unsigned long long u64;
typedef float v2f __attribute__((ext_vector_type(2)));

// Packed fp32 ops (VOP3P, 2 points/inst). Per-half rounding is IEEE rn —
// bit-identical to scalar __fadd_rn/__fmul_rn.
__device__ __forceinline__ v2f pk_add(v2f a, v2f b) {
  v2f r;
  asm("v_pk_add_f32 %0, %1, %2" : "=v"(r) : "v"(a), "v"(b));
  return r;
}
__device__ __forceinline__ v2f pk_mul(v2f a, v2f b) {
  v2f r;
  asm("v_pk_mul_f32 %0, %1, %2" : "=v"(r) : "v"(a), "v"(b));
  return r;
}

template <int CTRL>
__device__ __forceinline__ float dpp_maxf(float x) {
  // old=0 is the identity for max of non-negative values
  int m = __builtin_amdgcn_update_dpp(0, __float_as_int(x), CTRL, 0xf, 0xf, false);
  return fmaxf(x, __int_as_float(m));
}
template <int CTRL>
__device__ __forceinline__ u32 dpp_maxu(u32 x) {
  u32 m = (u32)__builtin_amdgcn_update_dpp(0, (int)x, CTRL, 0xf, 0xf, false);
  return (x > m) ? x : m;
}

// ---------------------------------------------------------------------------
// K1: farthest point sampling, fp32, bit-exact vs numpy. 256 thr/block,
// 32 pts/thread (v2f regs, asm-pinned), 1 wave/SIMD. r13: r10's structure
// with the serial chain halved — ONE barrier/iter. Value DPP max ->
// readlane(63) = WAVE max (SALU broadcast, no LDS) -> r10-shape find pass
// (4 inst/j, NO coord tracking — r11's +190cyc mistake) -> cand DPP max ->
// lane63 (holds both wave max and wave cand; no owner search) writes ONE
// packed u64 (dist<<32 | NN-idx) -> barrier -> all threads max 4 contiguous
// keys = global (max dist, tie -> lowest idx) = np.argmax. Center coords from
// LDS-staged point cloud (96 KB, 1 block/CU anyway): broadcast ds_read ~120cyc
// vs global L2 ~250cyc. Exactness: wave max is bit-identical to one of that
// wave's dm values; key algebra unchanged from r10.
// ---------------------------------------------------------------------------
__global__ __attribute__((amdgpu_flat_work_group_size(256, 256),
                          amdgpu_waves_per_eu(1, 1)))
void k_fps(const float* __restrict__ xyz, float* __restrict__ out_kp) {
  __shared__ float sxyz[NN * 3];  // [idx][x,y,z]
  __shared__ int sIdx[SS];
  __shared__ u64 rkey[2][4];
  int b = blockIdx.x, t = threadIdx.x;
  const float* base = xyz + b * N3;
  v2f px[16], py[16], pz[16], dm[16];
#pragma unroll
  for (int j = 0; j < 16; ++j) {
    int n0 = j * 512 + t, n1 = n0 + 256;  // coalesced, disjoint cover [0,8192)
    px[j] = v2f{base[n0], base[n1]};
    py[j] = v2f{base[NN + n0], base[NN + n1]};
    pz[j] = v2f{base[2 * NN + n0], base[2 * NN + n1]};
    dm[j] = v2f{1e10f, 1e10f};
    sxyz[n0 * 3 + 0] = px[j].x;  // stage AoS copy for center re-loads
    sxyz[n0 * 3 + 1] = py[j].x;
    sxyz[n0 * 3 + 2] = pz[j].x;
    sxyz[n1 * 3 + 0] = px[j].y;
    sxyz[n1 * 3 + 1] = py[j].y;
    sxyz[n1 * 3 + 2] = pz[j].y;
  }
#pragma unroll
  for (int j = 0; j < 16; ++j) {
    // Opaque def: blocks rematerialization of the global loads.
    asm volatile("" : "+v"(px[j]), "+v"(py[j]), "+v"(pz[j]));
  }
  // staging writes become visible at iter-0's barrier, before first LDS read
  float cx = base[0], cy = base[NN], cz = base[2 * NN];
  int far = 0;
  int lane = t & 63, w = t >> 6;
  u32 tb = (u32)(NN - t);  // candidate base: cand = NN - gidx (1..8192; 0=none)
  for (int it = 0; it < SS; ++it) {
    if (t == 0) sIdx[it] = far;  // scan emits carry BEFORE update: idx[0]=0
    // negated center, broadcast to both halves (a + (-c) == a - c exactly)
    v2f ncx = v2f{-cx, -cx}, ncy = v2f{-cy, -cy}, ncz = v2f{-cz, -cz};
    float vmax = 0.0f;
#pragma unroll
    for (int j = 0; j < 16; ++j) {
      v2f dx = pk_add(px[j], ncx);
      v2f dy = pk_add(py[j], ncy);
      v2f dz = pk_add(pz[j], ncz);
      v2f xx = pk_mul(dx, dx);
      v2f yy = pk_mul(dy, dy);
      v2f s = pk_add(xx, yy);
      v2f zz = pk_mul(dz, dz);
      v2f d = pk_add(s, zz);  // ((dx^2+dy^2)+dz^2), numpy tree per half
      float a0 = fminf(dm[j].x, d.x);
      float a1 = fminf(dm[j].y, d.y);
      dm[j].x = a0;
      dm[j].y = a1;
      vmax = fmaxf(vmax, fmaxf(a0, a1));  // max3-foldable
    }
    // wave max (single chain, distances >= 0), then SALU broadcast
    vmax = dpp_maxf<0x111>(vmax);  // row_shr:1
    vmax = dpp_maxf<0x112>(vmax);  // row_shr:2
    vmax = dpp_maxf<0x114>(vmax);  // row_shr:4
    vmax = dpp_maxf<0x118>(vmax);  // row_shr:8
    vmax = dpp_maxf<0x142>(vmax);  // row_bcast:15
    vmax = dpp_maxf<0x143>(vmax);  // row_bcast:31 -> lane63 = wave max
    float wv = __int_as_float(__builtin_amdgcn_readlane(__float_as_int(vmax), 63));
    // find pass vs WAVE max: exact bit-equality (wv IS one of this wave's dm
    // values); descending gidx order so the LAST write = lowest gidx.
    u32 cand = 0;
#pragma unroll
    for (int j = 15; j >= 0; --j) {
      u32 v1 = tb - (u32)(j * 512 + 256);  // cand for .y half (higher gidx)
      u32 v0 = tb - (u32)(j * 512);        // cand for .x half
      cand = (dm[j].y == wv) ? v1 : cand;
      cand = (dm[j].x == wv) ? v0 : cand;
    }
    cand = dpp_maxu<0x111>(cand);
    cand = dpp_maxu<0x112>(cand);
    cand = dpp_maxu<0x114>(cand);
    cand = dpp_maxu<0x118>(cand);
    cand = dpp_maxu<0x142>(cand);
    cand = dpp_maxu<0x143>(cand);  // lane63 = wave best (max cand = min gidx)
    int pb = it & 1;  // parity double-buffer: safe with one barrier/iter
    if (lane == 63) rkey[pb][w] = ((u64)__float_as_uint(wv) << 32) | cand;
    __syncthreads();  // the only barrier per iteration
    u64 k0 = rkey[pb][0], k1 = rkey[pb][1];
    u64 k2 = rkey[pb][2], k3 = rkey[pb][3];
    u64 k01 = (k0 > k1) ? k0 : k1;
    u64 k23 = (k2 > k3) ? k2 : k3;
    u64 kg = (k01 > k23) ? k01 : k23;
    far = NN - (int)(u32)(kg & 0xffffffffu);
    // broadcast ds_read of the winner's coords (all lanes same address)
    cx = sxyz[far * 3 + 0];
    cy = sxyz[far * 3 + 1];
    cz = sxyz[far * 3 + 2];
  }
  __syncthreads();
  for (int i = t; i < SS; i += 256) {
    int id = sIdx[i];
    out_kp[b * 1536 + i] = base[id];  // exact fp32 copies
    out_kp[b * 1536 + SS + i] = base[NN + id];
    out_kp[b * 1536 + 2 * SS + i] = base[2 * NN + id];
  }
}

// ---------------------------------------------------------------------------
// K2: per (b,s) row, sorted top-24 nearest (dist asc, idx asc) — prefixes give
// K=8/16/24 and base K=16 (lax.top_k stable tie-break). One wave per row.
// KD=14 per-lane depth (r11 win: non-fps time 634 -> 466 us): top-24 indices
// are ~uniform mod 64, P(any lane holds >=15 of 24) < 1e-15 over all rows.
// d = (|a|^2+|q|^2) - 2*dot, all rn ops, matching the numpy expression tree.
// ---------------------------------------------------------------------------
__global__ __launch_bounds__(256) void k_knn(const float* __restrict__ xyz,
                                             const float* __restrict__ kp,
                                             u16* __restrict__ knn) {
  int t = threadIdx.x;
  int row = blockIdx.x * 4 + (t >> 6);
  int lane = t & 63;
  int b = row >> 9, s = row & (SS - 1);
  const float* base = xyz + b * N3;
  float ax = kp[b * 1536 + s];
  float ay = kp[b * 1536 + SS + s];
  float az = kp[b * 1536 + 2 * SS + s];
  float aw = __fadd_rn(__fadd_rn(__fmul_rn(ax, ax), __fmul_rn(ay, ay)), __fmul_rn(az, az));
  u64 arr[KD];
#pragma unroll
  for (int i = 0; i < KD; ++i) arr[i] = ~0ull;
  for (int c = 0; c < 128; ++c) {
    int n = c * 64 + lane;
    float qx = base[n], qy = base[NN + n], qz = base[2 * NN + n];
    float qw = __fadd_rn(__fadd_rn(__fmul_rn(qx, qx), __fmul_rn(qy, qy)), __fmul_rn(qz, qz));
    float dot = __fadd_rn(__fadd_rn(__fmul_rn(ax, qx), __fmul_rn(ay, qy)), __fmul_rn(az, qz));
    float d = __fsub_rn(__fadd_rn(aw, qw), __fmul_rn(2.0f, dot));
    u32 ub = __float_as_uint(d);
    ub ^= (ub & 0x80000000u) ? 0xFFFFFFFFu : 0x80000000u;  // order-preserving map
    u64 key = ((u64)ub << 32) | (u32)n;
    if (key < arr[KD - 1]) {  // branchless descending insertion (arr asc)
#pragma unroll
      for (int i = KD - 1; i >= 1; --i) {
        u64 am = arr[i - 1];
        arr[i] = (am > key) ? am : ((arr[i] > key) ? key : arr[i]);
      }
      if (arr[0] > key) arr[0] = key;
    }
  }
  // merge 64 sorted lists: 24 x (wave-min of heads, winner pops). keys unique.
  u64 mine = 0;
  for (int it = 0; it < 24; ++it) {
    u64 m = arr[0];
#pragma unroll
    for (int off = 1; off < 64; off <<= 1) {
      u64 o = __shfl_xor(m, off, 64);
      m = (o < m) ? o : m;
    }
    if (lane == it) mine = m;
    if (arr[0] == m) {
#pragma unroll
      for (int i = 0; i < KD - 1; ++i) arr[i] = arr[i + 1];
      arr[KD - 1] = ~0ull;
    }
  }
  if (lane < 24) knn[row * 24 + lane] = (u16)(mine & 0xFFFFu);
}

// ---------------------------------------------------------------------------
// K3: base SA MLP. feat[16][6] = [rel_xyz | pts]; 6->64 relu -> 64->128; max
// over K=16. Wave = one row; each thread owns 2 output channels (lane,
// lane+64) with W2 rows in registers; h1 read as explicit float4 broadcast.
// Block = 4 rows in flight x 2 groups = 8 rows.
// ---------------------------------------------------------------------------
__global__ __launch_bounds__(256) void k_base(
    const float* __restrict__ xyz, const float* __restrict__ pts,
    const float* __restrict__ kp, const u16* __restrict__ knn,
    const float* __restrict__ W1, const float* __restrict__ b1,
    const float* __restrict__ W2, const float* __restrict__ b2,
    float* __restrict__ out) {
  __shared__ float sW1T[6 * 64];     // [c][o]
  __shared__ float sb1[64];
  __shared__ float sfeat[4][16 * 6]; // [row][k*6+c]
  __shared__ float sh1[4][16 * 64];  // [row][k*64+o]
  int t = threadIdx.x, lane = t & 63, w = t >> 6;
  int b = blockIdx.x >> 6, s0 = (blockIdx.x & 63) * 8;
  for (int i = t; i < 384; i += 256) {
    int o = i / 6, c = i - o * 6;
    sW1T[c * 64 + o] = W1[i];
  }
  if (t < 64) sb1[t] = b1[t];
  float wgtA[64], wgtB[64];
#pragma unroll
  for (int j = 0; j < 64; ++j) {
    wgtA[j] = W2[lane * 64 + j];
    wgtB[j] = W2[(lane + 64) * 64 + j];
  }
  float b2A = b2[lane], b2B = b2[lane + 64];
  __syncthreads();
  for (int g = 0; g < 2; ++g) {
    for (int i = t; i < 384; i += 256) {  // 4 rows x 16 k x 6 c
      int rr = i / 96, rem = i - rr * 96, k = rem / 6, c = rem - k * 6;
      int s = s0 + g * 4 + rr, row = b * SS + s;
      int id = knn[row * 24 + k];  // first 16 of sorted top-24 = base KNN
      float val;
      if (c < 3) {
        val = __fsub_rn(xyz[b * N3 + c * NN + id], kp[b * 1536 + c * SS + s]);
      } else {
        val = pts[b * N3 + (c - 3) * NN + id];
      }
      sfeat[rr][k * 6 + c] = val;
    }
    __syncthreads();
#pragma unroll
    for (int m = 0; m < 16; ++m) {  // 4 rows x 1024 h1 entries / 256 thr
      int u = m * 256 + t;
      int rr = u >> 10, rem = u & 1023, k = rem >> 6, o = rem & 63;
      float acc = sb1[o];
#pragma unroll
      for (int c = 0; c < 6; ++c) acc = fmaf(sfeat[rr][k * 6 + c], sW1T[c * 64 + o], acc);
      sh1[rr][k * 64 + o] = fmaxf(acc, 0.f);
    }
    __syncthreads();
    float bestA = -1e30f, bestB = -1e30f;
#pragma unroll
    for (int k = 0; k < 16; ++k) {
      const float4* h4 = (const float4*)&sh1[w][k * 64];  // wave-uniform bcast
      float a0 = 0.f, a1 = 0.f;
#pragma unroll
      for (int j = 0; j < 16; ++j) {
        float4 hv = h4[j];
        a0 = fmaf(hv.x, wgtA[4 * j], a0);
        a0 = fmaf(hv.y, wgtA[4 * j + 1], a0);
        a0 = fmaf(hv.z, wgtA[4 * j + 2], a0);
        a0 = fmaf(hv.w, wgtA[4 * j + 3], a0);
        a1 = fmaf(hv.x, wgtB[4 * j], a1);
        a1 = fmaf(hv.y, wgtB[4 * j + 1], a1);
        a1 = fmaf(hv.z, wgtB[4 * j + 2], a1);
        a1 = fmaf(hv.w, wgtB[4 * j + 3], a1);
      }
      bestA = fmaxf(bestA, a0);
      bestB = fmaxf(bestB, a1);
    }
    int s = s0 + g * 4 + w;
    out[24576 + b * 262144 + lane * 512 + s] = bestA + b2A;
    out[24576 + b * 262144 + (lane + 64) * 512 + s] = bestB + b2B;
    __syncthreads();  // protect sfeat/sh1 before next group overwrites
  }
}

// ---------------------------------------------------------------------------
// K4: multi-scale MLPs, scale = blockIdx.y, K = 8*(scale+1), rel-xyz only.
// Same 2-channels-per-thread structure. Output channels 128*(scale+1)..+128.
// ---------------------------------------------------------------------------
__global__ __launch_bounds__(256) void k_ms(
    const float* __restrict__ xyz, const float* __restrict__ kp,
    const u16* __restrict__ knn, const float* __restrict__ msW1,
    const float* __restrict__ msb1, const float* __restrict__ msW2,
    const float* __restrict__ msb2, float* __restrict__ out) {
  int scale = blockIdx.y;
  int kk = 8 * (scale + 1);
  __shared__ float sW1T[3 * 64];
  __shared__ float sb1[64];
  __shared__ float sfeat[4][24 * 3];
  __shared__ float sh1[4][24 * 64];
  int t = threadIdx.x, lane = t & 63, w = t >> 6;
  int b = blockIdx.x >> 6, s0 = (blockIdx.x & 63) * 8;
  const float* W1s = msW1 + scale * 192;
  for (int i = t; i < 192; i += 256) {
    int o = i / 3, c = i - o * 3;
    sW1T[c * 64 + o] = W1s[i];
  }
  if (t < 64) sb1[t] = msb1[scale * 64 + t];
  float wgtA[64], wgtB[64];
#pragma unroll
  for (int j = 0; j < 64; ++j) {
    wgtA[j] = msW2[scale * 8192 + lane * 64 + j];
    wgtB[j] = msW2[scale * 8192 + (lane + 64) * 64 + j];
  }
  float b2A = msb2[scale * 128 + lane], b2B = msb2[scale * 128 + lane + 64];
  __syncthreads();
  int co = 128 * (scale + 1);
  for (int g = 0; g < 2; ++g) {
    int nfeat = 4 * kk * 3;
    for (int i = t; i < nfeat; i += 256) {  // 4 rows x kk k x 3 c
      int kk3 = kk * 3;
      int rr = i / kk3, rem = i - rr * kk3, k = rem / 3, c = rem - k * 3;
      int s = s0 + g * 4 + rr, row = b * SS + s;
      int id = knn[row * 24 + k];
      sfeat[rr][k * 3 + c] = __fsub_rn(xyz[b * N3 + c * NN + id], kp[b * 1536 + c * SS + s]);
    }
    __syncthreads();
    for (int rr = 0; rr < 4; ++rr) {  // h1 for kk*64 entries per row
      for (int u = t; u < kk * 64; u += 256) {
        int k = u >> 6, o = u & 63;
        float acc = sb1[o];
        acc = fmaf(sfeat[rr][k * 3 + 0], sW1T[o], acc);
        acc = fmaf(sfeat[rr][k * 3 + 1], sW1T[64 + o], acc);
        acc = fmaf(sfeat[rr][k * 3 + 2], sW1T[128 + o], acc);
        sh1[rr][k * 64 + o] = fmaxf(acc, 0.f);
      }
    }
    __syncthreads();
    float bestA = -1e30f, bestB = -1e30f;
    for (int k = 0; k < kk; ++k) {  // kk uniform across block -> no divergence
      const float4* h4 = (const float4*)&sh1[w][k * 64];
      float a0 = 0.f, a1 = 0.f;
#pragma unroll
      for (int j = 0; j < 16; ++j) {
        float4 hv = h4[j];
        a0 = fmaf(hv.x, wgtA[4 * j], a0);
        a0 = fmaf(hv.y, wgtA[4 * j + 1], a0);
        a0 = fmaf(hv.z, wgtA[4 * j + 2], a0);
        a0 = fmaf(hv.w, wgtA[4 * j + 3], a0);
        a1 = fmaf(hv.x, wgtB[4 * j], a1);
        a1 = fmaf(hv.y, wgtB[4 * j + 1], a1);
        a1 = fmaf(hv.z, wgtB[4 * j + 2], a1);
        a1 = fmaf(hv.w, wgtB[4 * j + 3], a1);
      }
      bestA = fmaxf(bestA, a0);
      bestB = fmaxf(bestB, a1);
    }
    int s = s0 + g * 4 + w;
    out[24576 + b * 262144 + (co + lane) * 512 + s] = bestA + b2A;
    out[24576 + b * 262144 + (co + lane + 64) * 512 + s] = bestB + b2B;
    __syncthreads();
  }
}

// ---------------------------------------------------------------------------
extern "C" void kernel_launch(void* const* d_in, const int* in_sizes, int n_in,
                              void* d_out, int out_size, void* d_ws, size_t ws_size,
                              hipStream_t stream) {
  const float* xyz = (const float*)d_in[0];    // l0_xyz  [B,3,N] f32
  const float* pts = (const float*)d_in[1];    // l0_points
  const float* sa_W1 = (const float*)d_in[2];  // [64,6]
  const float* sa_b1 = (const float*)d_in[3];  // [64]
  const float* sa_W2 = (const float*)d_in[4];  // [128,64]
  const float* sa_b2 = (const float*)d_in[5];  // [128]
  const float* ms_W1 = (const float*)d_in[6];  // [3,64,3]
  const float* ms_b1 = (const float*)d_in[7];  // [3,64]
  const float* ms_W2 = (const float*)d_in[8];  // [3,128,64]
  const float* ms_b2 = (const float*)d_in[9];  // [3,128]
  float* out = (float*)d_out;
  const float* kp = (const float*)d_out;  // keypoints written by k_fps

  // workspace: knn u16[B*S*24] = 384 KB
  u16* knn = (u16*)d_ws;

  k_fps<<<BB, 256, 0, stream>>>(xyz, out);
  k_knn<<<(BB * SS) / 4, 256, 0, stream>>>(xyz, kp, knn);
  k_base<<<BB * 64, 256, 0, stream>>>(xyz, pts, kp, knn, sa_W1, sa_b1, sa_W2, sa_b2, out);
  k_ms<<<dim3(BB * 64, 3), 256, 0, stream>>>(xyz, kp, knn, ms_W1, ms_b1, ms_W2, ms_b2, out);
}